// Round 1
// baseline (500.910 us; speedup 1.0000x reference)
//
#include <hip/hip_runtime.h>

// PatchAttentionLayer: algebraically restructured.
//   B=8, C=256, N=64*64=4096 pixels/batch, P=B*N=32768.
//   G_b = x_b x_b^T (C x C), s_b = x_b 1
//   BN stats analytic from Ghat = sum_b G_b / P and xbar.
//   M_b = scale*(Wv' G_b Wk'^T + u_b ck^T + cv w_b^T + N cv ck^T)
//   T_b = M_b Wq', off_b = M_b cq, out_b = T_b x_b + off_b 1^T.
// Workspace: ~9.2 MB fp32.

#define BB 8
#define CC 256
#define NPIX 4096
#define PTOT 32768
#define EPSV 1e-5f
#define SCALEV 0.125f   // h^{-0.5} = 64^{-0.5}

// ---- workspace layout (float offsets) ----
#define OFF_G     0L          // B*C*C = 524288
#define OFF_S     524288L     // B*C   = 2048
#define OFF_GHAT  526336L     // 65536
#define OFF_XBAR  591872L     // 256
#define OFF_WALL  592128L     // 3*65536
#define OFF_H     788736L     // 3*65536
#define OFF_WP    985344L     // 3*65536 (Wq',Wk',Wv')
#define OFF_CVEC  1181952L    // 768 (cq,ck,cv)
#define OFF_AVEC  1182720L    // 768
#define OFF_U     1183488L    // B*C
#define OFF_W     1185536L    // B*C
#define OFF_HB    1187584L    // B*C
#define OFF_GY    1189632L    // B*C
#define OFF_Y     1191680L    // 256
#define OFF_R     1191936L    // 256
#define OFF_OFFV  1192192L    // B*C
#define OFF_Z     1194240L    // 65536
#define OFF_F     1259776L    // B*C*C
#define OFF_T     1784064L    // B*C*C
// total 2308352 floats = 9.23 MB

__device__ __forceinline__ float block_reduce(float v, float* red, int tid) {
    red[tid] = v; __syncthreads();
    for (int st = 128; st > 0; st >>= 1) {
        if (tid < st) red[tid] += red[tid + st];
        __syncthreads();
    }
    float r = red[0]; __syncthreads();
    return r;
}

// ---- Gram: G_b += x_b[i,:] . x_b[j,:] over a K-slice (atomicAdd) ----
__global__ void gram_kernel(const float* __restrict__ x, float* __restrict__ G) {
    __shared__ float Xi[32][68];
    __shared__ float Xj[32][68];
    const int tx = threadIdx.x, ty = threadIdx.y;
    const int tid = ty * 16 + tx;
    const int jt = blockIdx.x, it = blockIdx.y;
    const int bz = blockIdx.z;
    const int b = bz >> 3, ks = bz & 7;
    const int i0 = it * 64, j0 = jt * 64, k0 = ks * 512;
    const float* xb = x + (long)b * CC * NPIX;
    float acc[4][4] = {};
    for (int kc = 0; kc < 512; kc += 32) {
        for (int l = tid; l < 512; l += 256) {
            const int i = l >> 3, kq = l & 7;
            const float4 v = *(const float4*)&xb[(long)(i0 + i) * NPIX + k0 + kc + kq * 4];
            Xi[kq * 4 + 0][i] = v.x; Xi[kq * 4 + 1][i] = v.y;
            Xi[kq * 4 + 2][i] = v.z; Xi[kq * 4 + 3][i] = v.w;
            const float4 u = *(const float4*)&xb[(long)(j0 + i) * NPIX + k0 + kc + kq * 4];
            Xj[kq * 4 + 0][i] = u.x; Xj[kq * 4 + 1][i] = u.y;
            Xj[kq * 4 + 2][i] = u.z; Xj[kq * 4 + 3][i] = u.w;
        }
        __syncthreads();
        #pragma unroll
        for (int kk = 0; kk < 32; ++kk) {
            const float4 a4 = *(const float4*)&Xi[kk][ty * 4];
            const float4 b4 = *(const float4*)&Xj[kk][tx * 4];
            const float av[4] = {a4.x, a4.y, a4.z, a4.w};
            const float bv[4] = {b4.x, b4.y, b4.z, b4.w};
            #pragma unroll
            for (int a = 0; a < 4; ++a)
                #pragma unroll
                for (int q = 0; q < 4; ++q) acc[a][q] += av[a] * bv[q];
        }
        __syncthreads();
    }
    float* Gb = G + (long)b * CC * CC;
    #pragma unroll
    for (int a = 0; a < 4; ++a)
        #pragma unroll
        for (int q = 0; q < 4; ++q)
            atomicAdd(&Gb[(long)(i0 + ty * 4 + a) * CC + j0 + tx * 4 + q], acc[a][q]);
}

// ---- per-channel row sums s_b[c] ----
__global__ void rowsum_kernel(const float* __restrict__ x, float* __restrict__ s) {
    const int c = blockIdx.x, b = blockIdx.y, tid = threadIdx.x;
    const float* base = x + ((long)b * CC + c) * NPIX;
    float v = 0.f;
    for (int i = tid; i < NPIX; i += 256) v += base[i];
    __shared__ float red[256];
    red[tid] = v; __syncthreads();
    for (int st = 128; st > 0; st >>= 1) {
        if (tid < st) red[tid] += red[tid + st];
        __syncthreads();
    }
    if (tid == 0) s[b * CC + c] = red[0];
}

// ---- Ghat = sum_b G_b / P ; xbar = sum_b s_b / P ----
__global__ void reduceG_kernel(const float* __restrict__ G, const float* __restrict__ s,
                               float* __restrict__ Ghat, float* __restrict__ xbar) {
    const int bid = blockIdx.x, tid = threadIdx.x;
    if (bid < 256) {
        const int idx = bid * 256 + tid;
        float sum = 0.f;
        for (int b = 0; b < BB; ++b) sum += G[(long)b * 65536 + idx];
        Ghat[idx] = sum * (1.0f / PTOT);
    } else {
        float sum = 0.f;
        for (int b = 0; b < BB; ++b) sum += s[b * CC + tid];
        xbar[tid] = sum * (1.0f / PTOT);
    }
}

// ---- pack Wq,Wk,Wv contiguous ----
__global__ void copywall_kernel(const float* __restrict__ Wq, const float* __restrict__ Wk,
                                const float* __restrict__ Wv, float* __restrict__ Wall) {
    const int idx = blockIdx.x * 256 + threadIdx.x;   // 0..196607
    const float* src = idx < 65536 ? Wq : (idx < 131072 ? Wk : Wv);
    Wall[idx] = src[idx & 65535];
}

// ---- generic 64x64-tile fp32 GEMM, sizes multiples of 64, batched via strides ----
__global__ void gemm64(const float* __restrict__ A, const float* __restrict__ B,
                       float* __restrict__ Cm, int M, int N, int K,
                       int transA, int transB, long sA, long sB, long sC) {
    __shared__ float As[16][68];
    __shared__ float Bs[16][68];
    const int tx = threadIdx.x, ty = threadIdx.y;
    const int tid = ty * 16 + tx;
    const int n0 = blockIdx.x * 64, m0 = blockIdx.y * 64, bz = blockIdx.z;
    A += (long)bz * sA; B += (long)bz * sB; Cm += (long)bz * sC;
    float acc[4][4] = {};
    for (int k0 = 0; k0 < K; k0 += 16) {
        if (!transA) {
            for (int l = tid; l < 1024; l += 256) {
                const int m = l >> 4, kk = l & 15;
                As[kk][m] = A[(long)(m0 + m) * K + k0 + kk];
            }
        } else {
            for (int l = tid; l < 1024; l += 256) {
                const int kk = l >> 6, m = l & 63;
                As[kk][m] = A[(long)(k0 + kk) * M + m0 + m];
            }
        }
        if (!transB) {
            for (int l = tid; l < 1024; l += 256) {
                const int kk = l >> 6, n = l & 63;
                Bs[kk][n] = B[(long)(k0 + kk) * N + n0 + n];
            }
        } else {
            for (int l = tid; l < 1024; l += 256) {
                const int n = l >> 4, kk = l & 15;
                Bs[kk][n] = B[(long)(n0 + n) * K + k0 + kk];
            }
        }
        __syncthreads();
        #pragma unroll
        for (int kk = 0; kk < 16; ++kk) {
            const float4 a4 = *(const float4*)&As[kk][ty * 4];
            const float4 b4 = *(const float4*)&Bs[kk][tx * 4];
            const float av[4] = {a4.x, a4.y, a4.z, a4.w};
            const float bv[4] = {b4.x, b4.y, b4.z, b4.w};
            #pragma unroll
            for (int a = 0; a < 4; ++a)
                #pragma unroll
                for (int q = 0; q < 4; ++q) acc[a][q] += av[a] * bv[q];
        }
        __syncthreads();
    }
    #pragma unroll
    for (int a = 0; a < 4; ++a)
        #pragma unroll
        for (int q = 0; q < 4; ++q)
            Cm[(long)(m0 + ty * 4 + a) * N + n0 + tx * 4 + q] = acc[a][q];
}

// ---- BN coefficients: mu, var analytic; write Wp = diag(a) W, cvec ----
__global__ void stats_kernel(const float* __restrict__ Wall, const float* __restrict__ H,
                             const float* __restrict__ xbar,
                             const float* bq, const float* gq, const float* betaq,
                             const float* bk, const float* gk, const float* betak,
                             const float* bv, const float* gv, const float* betav,
                             float* __restrict__ Wp, float* __restrict__ avec,
                             float* __restrict__ cvec) {
    const int o = blockIdx.x, t = blockIdx.y, tid = threadIdx.x;
    const float* bt  = t == 0 ? bq    : (t == 1 ? bk    : bv);
    const float* gt  = t == 0 ? gq    : (t == 1 ? gk    : gv);
    const float* bet = t == 0 ? betaq : (t == 1 ? betak : betav);
    __shared__ float wrow[256];
    __shared__ float red[256];
    wrow[tid] = Wall[(long)t * 65536 + o * 256 + tid];
    __syncthreads();
    const float wx = block_reduce(wrow[tid] * xbar[tid], red, tid);
    const float q2 = block_reduce(wrow[tid] * H[(long)t * 65536 + tid * 256 + o], red, tid);
    const float bo = bt[o];
    const float mu = wx + bo;
    const float var = q2 + 2.f * bo * mu - bo * bo - mu * mu;
    const float a = gt[o] * rsqrtf(var + EPSV);
    Wp[(long)t * 65536 + o * 256 + tid] = a * wrow[tid];
    if (tid == 0) {
        avec[t * 256 + o] = a;
        cvec[t * 256 + o] = a * (bo - mu) + bet[o];
    }
}

// ---- u_b = Wv' s_b ; w_b = Wk' s_b ; y = Wk'^T cq ; r = Wq'^T ck ----
__global__ void vec1_kernel(const float* __restrict__ Wp, const float* __restrict__ s,
                            const float* __restrict__ cvec, float* __restrict__ u,
                            float* __restrict__ w, float* __restrict__ y,
                            float* __restrict__ r) {
    const int bidx = blockIdx.x, tid = threadIdx.x;
    __shared__ float sh[256];
    if (bidx < 8) {
        sh[tid] = s[bidx * CC + tid]; __syncthreads();
        float uu = 0.f, ww = 0.f;
        for (int j = 0; j < 256; ++j) {
            uu += Wp[2 * 65536 + tid * 256 + j] * sh[j];
            ww += Wp[1 * 65536 + tid * 256 + j] * sh[j];
        }
        u[bidx * CC + tid] = uu; w[bidx * CC + tid] = ww;
    } else if (bidx == 8) {
        sh[tid] = cvec[0 * 256 + tid]; __syncthreads();   // cq
        float yy = 0.f;
        for (int o = 0; o < 256; ++o) yy += Wp[1 * 65536 + o * 256 + tid] * sh[o];
        y[tid] = yy;
    } else {
        sh[tid] = cvec[1 * 256 + tid]; __syncthreads();   // ck
        float rr = 0.f;
        for (int o = 0; o < 256; ++o) rr += Wp[0 * 65536 + o * 256 + tid] * sh[o];
        r[tid] = rr;
    }
}

// ---- h_b = Wq'^T w_b ; gy_b = G_b y ----
__global__ void vec2_kernel(const float* __restrict__ Wp, const float* __restrict__ G,
                            const float* __restrict__ w, const float* __restrict__ y,
                            float* __restrict__ h, float* __restrict__ gy) {
    const int b = blockIdx.x, tid = threadIdx.x;
    __shared__ float wl[256];
    __shared__ float yl[256];
    wl[tid] = w[b * CC + tid]; yl[tid] = y[tid]; __syncthreads();
    float hh = 0.f, gg = 0.f;
    for (int o = 0; o < 256; ++o) hh += Wp[0 * 65536 + o * 256 + tid] * wl[o];
    for (int j = 0; j < 256; ++j) gg += G[(long)b * 65536 + tid * 256 + j] * yl[j];
    h[b * CC + tid] = hh; gy[b * CC + tid] = gg;
}

// ---- off_b assembly + T rank-1 updates + scale ----
__global__ void finalize_kernel(const float* __restrict__ Wp, const float* __restrict__ cvec,
                                const float* __restrict__ u, const float* __restrict__ w,
                                const float* __restrict__ hb, const float* __restrict__ gy,
                                const float* __restrict__ r, float* __restrict__ offv,
                                float* __restrict__ T) {
    const int b = blockIdx.x, tid = threadIdx.x;
    __shared__ float gyl[256];
    __shared__ float red[256];
    __shared__ float ul[256];
    __shared__ float cvl[256];
    gyl[tid] = gy[b * CC + tid];
    ul[tid] = u[b * CC + tid];
    cvl[tid] = cvec[2 * 256 + tid];
    __syncthreads();
    float vg = 0.f;
    for (int j = 0; j < 256; ++j) vg += Wp[2 * 65536 + tid * 256 + j] * gyl[j];
    const float cq_ = cvec[0 * 256 + tid], ck_ = cvec[1 * 256 + tid];
    const float dkq = block_reduce(cq_ * ck_, red, tid);
    const float dwq = block_reduce(w[b * CC + tid] * cq_, red, tid);
    offv[b * CC + tid] = SCALEV * (vg + ul[tid] * dkq + cvl[tid] * (dwq + 4096.0f * dkq));
    __syncthreads();
    const float rv = r[tid];
    const float hv = hb[b * CC + tid];
    const float t2 = hv + 4096.0f * rv;
    const long base = (long)b * 65536;
    for (int i = 0; i < 256; ++i) {
        const long idx = base + (long)i * 256 + tid;
        T[idx] = SCALEV * (T[idx] + ul[i] * rv + cvl[i] * t2);
    }
}

// ---- out_b = T_b x_b + off_b ----
__global__ void out_kernel(const float* __restrict__ T, const float* __restrict__ x,
                           const float* __restrict__ offv, float* __restrict__ out) {
    __shared__ float Ts[16][68];
    __shared__ float xs[16][132];
    __shared__ float offl[64];
    const int tx = threadIdx.x, ty = threadIdx.y;
    const int tid = ty * 16 + tx;
    const int p0 = blockIdx.x * 128, i0 = blockIdx.y * 64, b = blockIdx.z;
    const float* Tb = T + (long)b * 65536;
    const float* xb = x + (long)b * CC * NPIX;
    if (tid < 64) offl[tid] = offv[b * CC + i0 + tid];
    float acc[4][8] = {};
    for (int k0 = 0; k0 < 256; k0 += 16) {
        for (int l = tid; l < 1024; l += 256) {
            const int m = l >> 4, kk = l & 15;
            Ts[kk][m] = Tb[(long)(i0 + m) * 256 + k0 + kk];
        }
        for (int l = tid; l < 2048; l += 256) {
            const int kk = l >> 7, j = l & 127;
            xs[kk][j] = xb[(long)(k0 + kk) * NPIX + p0 + j];
        }
        __syncthreads();
        #pragma unroll
        for (int kk = 0; kk < 16; ++kk) {
            const float4 t4 = *(const float4*)&Ts[kk][ty * 4];
            const float tv[4] = {t4.x, t4.y, t4.z, t4.w};
            const float4 x1 = *(const float4*)&xs[kk][tx * 8];
            const float4 x2 = *(const float4*)&xs[kk][tx * 8 + 4];
            const float xv[8] = {x1.x, x1.y, x1.z, x1.w, x2.x, x2.y, x2.z, x2.w};
            #pragma unroll
            for (int a = 0; a < 4; ++a)
                #pragma unroll
                for (int q = 0; q < 8; ++q) acc[a][q] += tv[a] * xv[q];
        }
        __syncthreads();
    }
    #pragma unroll
    for (int a = 0; a < 4; ++a) {
        const int row = i0 + ty * 4 + a;
        const float o_ = offl[ty * 4 + a];
        float4 r1, r2;
        r1.x = acc[a][0] + o_; r1.y = acc[a][1] + o_; r1.z = acc[a][2] + o_; r1.w = acc[a][3] + o_;
        r2.x = acc[a][4] + o_; r2.y = acc[a][5] + o_; r2.z = acc[a][6] + o_; r2.w = acc[a][7] + o_;
        float* dst = &out[((long)b * CC + row) * NPIX + p0 + tx * 8];
        *(float4*)dst = r1;
        *(float4*)(dst + 4) = r2;
    }
}

extern "C" void kernel_launch(void* const* d_in, const int* in_sizes, int n_in,
                              void* d_out, int out_size, void* d_ws, size_t ws_size,
                              hipStream_t stream) {
    const float* x     = (const float*)d_in[0];
    const float* Wq    = (const float*)d_in[1];
    const float* bq    = (const float*)d_in[2];
    const float* gq    = (const float*)d_in[3];
    const float* betaq = (const float*)d_in[4];
    const float* Wk    = (const float*)d_in[5];
    const float* bk    = (const float*)d_in[6];
    const float* gk    = (const float*)d_in[7];
    const float* betak = (const float*)d_in[8];
    const float* Wv    = (const float*)d_in[9];
    const float* bv    = (const float*)d_in[10];
    const float* gv    = (const float*)d_in[11];
    const float* betav = (const float*)d_in[12];
    float* ws = (float*)d_ws;

    float* G    = ws + OFF_G;
    float* S    = ws + OFF_S;
    float* Ghat = ws + OFF_GHAT;
    float* xbar = ws + OFF_XBAR;
    float* Wall = ws + OFF_WALL;
    float* H    = ws + OFF_H;
    float* Wp   = ws + OFF_WP;
    float* cvec = ws + OFF_CVEC;
    float* avec = ws + OFF_AVEC;
    float* U    = ws + OFF_U;
    float* W_   = ws + OFF_W;
    float* Hb   = ws + OFF_HB;
    float* Gy   = ws + OFF_GY;
    float* Y    = ws + OFF_Y;
    float* R    = ws + OFF_R;
    float* OffV = ws + OFF_OFFV;
    float* Z    = ws + OFF_Z;
    float* F    = ws + OFF_F;
    float* T    = ws + OFF_T;

    // zero G and s (atomicAdd targets)
    hipMemsetAsync(d_ws, 0, (size_t)(OFF_S + BB * CC) * sizeof(float), stream);

    gram_kernel<<<dim3(4, 4, 64), dim3(16, 16), 0, stream>>>(x, G);
    rowsum_kernel<<<dim3(256, 8), 256, 0, stream>>>(x, S);
    reduceG_kernel<<<257, 256, 0, stream>>>(G, S, Ghat, xbar);
    copywall_kernel<<<768, 256, 0, stream>>>(Wq, Wk, Wv, Wall);
    // H_t = Ghat @ W_t^T  (batch 3)
    gemm64<<<dim3(4, 4, 3), dim3(16, 16), 0, stream>>>(Ghat, Wall, H, 256, 256, 256,
                                                       0, 1, 0L, 65536L, 65536L);
    stats_kernel<<<dim3(256, 3), 256, 0, stream>>>(Wall, H, xbar, bq, gq, betaq,
                                                   bk, gk, betak, bv, gv, betav,
                                                   Wp, avec, cvec);
    vec1_kernel<<<10, 256, 0, stream>>>(Wp, S, cvec, U, W_, Y, R);
    // Z = Wk'^T @ Wq'
    gemm64<<<dim3(4, 4, 1), dim3(16, 16), 0, stream>>>(Wp + 65536, Wp, Z, 256, 256, 256,
                                                       1, 0, 0L, 0L, 0L);
    vec2_kernel<<<8, 256, 0, stream>>>(Wp, G, W_, Y, Hb, Gy);
    // F_b = G_b @ Z  (batch 8)
    gemm64<<<dim3(4, 4, 8), dim3(16, 16), 0, stream>>>(G, Z, F, 256, 256, 256,
                                                       0, 0, 65536L, 0L, 65536L);
    // T_b = Wv' @ F_b (batch 8)
    gemm64<<<dim3(4, 4, 8), dim3(16, 16), 0, stream>>>(Wp + 2 * 65536, F, T, 256, 256, 256,
                                                       0, 0, 0L, 65536L, 65536L);
    finalize_kernel<<<8, 256, 0, stream>>>(Wp, cvec, U, W_, Hb, Gy, R, OffV, T);
    out_kernel<<<dim3(32, 4, 8), dim3(16, 16), 0, stream>>>(T, x, OffV, (float*)d_out);
}

// Round 2
// 359.645 us; speedup vs baseline: 1.3928x; 1.3928x over previous
//
#include <hip/hip_runtime.h>

// PatchAttentionLayer, algebraically restructured + bf16 MFMA for the two
// big GEMMs (gram G_b = x_b x_b^T, and out_b = T_b x_b).
//   BN stats analytic from Ghat = sum_b G_b / P and xbar (quadratic form).
//   M_b = scale*(Wv' G_b Wk'^T + rank-1 terms); T_b = M_b Wq'; out = T_b x_b + off.
// G is symmetric: gram computes upper tiles only; mirror_reduce fills the rest.

#define BB 8
#define CC 256
#define NPIX 4096
#define PTOT 32768
#define EPSV 1e-5f
#define SCALEV 0.125f   // h^{-0.5} = 64^{-0.5}

// ---- workspace layout (float offsets) ----
#define OFF_G     0L          // 524288
#define OFF_S     524288L     // 2048
#define OFF_GHAT  526336L     // 65536
#define OFF_XBAR  591872L     // 256
#define OFF_WP    592128L     // 196608
#define OFF_CVEC  788736L     // 768
#define OFF_U     789504L     // 2048
#define OFF_W     791552L     // 2048
#define OFF_HB    793600L     // 2048
#define OFF_GY    795648L     // 2048
#define OFF_Y     797696L     // 256
#define OFF_R     797952L     // 256
#define OFF_OFFV  798208L     // 2048
#define OFF_Z     800256L     // 65536
#define OFF_F     865792L     // 524288
#define OFF_T     1390080L    // 524288
#define OFF_TBF   1914368L    // 131072 floats = 262144 ushort (bf16 T)
// total 2045440 floats = 8.18 MB

typedef __attribute__((ext_vector_type(8))) short short8;
typedef __attribute__((ext_vector_type(4))) float f32x4;

#define MFMA16(a, b, c) __builtin_amdgcn_mfma_f32_16x16x32_bf16((a), (b), (c), 0, 0, 0)

__device__ __forceinline__ ushort f2bf(float f) {
    union { float f; unsigned u; } v; v.f = f;
    const unsigned r = (v.u + 0x7FFFu + ((v.u >> 16) & 1u)) >> 16;
    return (ushort)r;
}

__device__ __forceinline__ float block_reduce(float v, float* red, int tid) {
    red[tid] = v; __syncthreads();
    for (int st = 128; st > 0; st >>= 1) {
        if (tid < st) red[tid] += red[tid + st];
        __syncthreads();
    }
    float r = red[0]; __syncthreads();
    return r;
}

// ---- Gram via MFMA: upper tiles only, rowsum fused on diagonal blocks ----
// grid (32 ks, 8 b, 3 tt): tt=0 -> (it,jt)=(0,0); tt=1 -> (1,1); tt=2 -> (0,1)
__global__ __launch_bounds__(256) void gram_mfma(const float* __restrict__ x,
                                                 float* __restrict__ G,
                                                 float* __restrict__ S) {
    __shared__ __align__(16) ushort Ab[128 * 72];
    __shared__ __align__(16) ushort Bb[128 * 72];
    const int tid = threadIdx.x;
    const int ks = blockIdx.x;
    const int b  = blockIdx.y;
    const int tt = blockIdx.z;
    const int it = (tt == 1) ? 1 : 0;
    const int jt = (tt == 0) ? 0 : 1;
    const bool diag = (tt < 2);
    const int i0 = it * 128, j0 = jt * 128, k0 = ks * 128;
    const float* xb = x + (long)b * CC * NPIX;
    const int r = tid >> 1, h = tid & 1;
    const float* arow = xb + (long)(i0 + r) * NPIX + k0 + h * 32;
    const float* brow = xb + (long)(j0 + r) * NPIX + k0 + h * 32;
    float rsum = 0.f;

    const int wave = tid >> 6, lane = tid & 63;
    const int wr = (wave >> 1) * 64, wc = (wave & 1) * 64;
    const int m = lane & 15, q8 = (lane >> 4) * 8;

    f32x4 acc[4][4];
    #pragma unroll
    for (int a = 0; a < 4; ++a)
        #pragma unroll
        for (int q = 0; q < 4; ++q) acc[a][q] = (f32x4){0.f, 0.f, 0.f, 0.f};

    for (int kt = 0; kt < 128; kt += 64) {
        #pragma unroll
        for (int j = 0; j < 8; ++j) {
            const float4 v = *(const float4*)(arow + kt + j * 4);
            rsum += v.x + v.y + v.z + v.w;
            ushort4 w;
            w.x = f2bf(v.x); w.y = f2bf(v.y); w.z = f2bf(v.z); w.w = f2bf(v.w);
            *(ushort4*)&Ab[r * 72 + h * 32 + j * 4] = w;
        }
        if (!diag) {
            #pragma unroll
            for (int j = 0; j < 8; ++j) {
                const float4 v = *(const float4*)(brow + kt + j * 4);
                ushort4 w;
                w.x = f2bf(v.x); w.y = f2bf(v.y); w.z = f2bf(v.z); w.w = f2bf(v.w);
                *(ushort4*)&Bb[r * 72 + h * 32 + j * 4] = w;
            }
        }
        __syncthreads();
        const ushort* Bsrc = diag ? Ab : Bb;
        #pragma unroll
        for (int kk = 0; kk < 2; ++kk) {
            short8 af[4], bfr[4];
            #pragma unroll
            for (int a = 0; a < 4; ++a)
                af[a] = *(const short8*)&Ab[(wr + a * 16 + m) * 72 + kk * 32 + q8];
            #pragma unroll
            for (int q = 0; q < 4; ++q)
                bfr[q] = *(const short8*)&Bsrc[(wc + q * 16 + m) * 72 + kk * 32 + q8];
            #pragma unroll
            for (int a = 0; a < 4; ++a)
                #pragma unroll
                for (int q = 0; q < 4; ++q)
                    acc[a][q] = MFMA16(af[a], bfr[q], acc[a][q]);
        }
        __syncthreads();
    }
    float* Gb = G + (long)b * 65536;
    const int rq = (lane >> 4) * 4;
    #pragma unroll
    for (int a = 0; a < 4; ++a) {
        const int gi = i0 + wr + a * 16 + rq;
        #pragma unroll
        for (int q = 0; q < 4; ++q) {
            const int gj = j0 + wc + q * 16 + m;
            #pragma unroll
            for (int reg = 0; reg < 4; ++reg)
                atomicAdd(&Gb[(long)(gi + reg) * 256 + gj], acc[a][q][reg]);
        }
    }
    if (diag) {
        rsum += __shfl_down(rsum, 1);
        if (h == 0) atomicAdd(&S[b * CC + i0 + r], rsum);
    }
}

// ---- mirror lower-left of G_b from upper-right; Ghat = sum_b G_b / P ; xbar ----
__global__ void mirror_reduce(float* __restrict__ G, const float* __restrict__ S,
                              float* __restrict__ Ghat, float* __restrict__ xbar) {
    const int i = blockIdx.x, tid = threadIdx.x;
    if (i < 256) {
        float sum = 0.f;
        if (i >= 128 && tid < 128) {
            for (int b = 0; b < BB; ++b) {
                const float v = G[(long)b * 65536 + (long)tid * 256 + i];
                G[(long)b * 65536 + (long)i * 256 + tid] = v;
                sum += v;
            }
        } else {
            for (int b = 0; b < BB; ++b)
                sum += G[(long)b * 65536 + (long)i * 256 + tid];
        }
        Ghat[i * 256 + tid] = sum * (1.0f / PTOT);
    } else {
        float sum = 0.f;
        for (int b = 0; b < BB; ++b) sum += S[b * CC + tid];
        xbar[tid] = sum * (1.0f / PTOT);
    }
}

// ---- BN stats via quadratic form q2[o] = w_o^T Ghat w_o ; writes Wp, cvec ----
__global__ void stats_quad(const float* __restrict__ Wq, const float* __restrict__ Wk,
                           const float* __restrict__ Wv, const float* __restrict__ Ghat,
                           const float* __restrict__ xbar,
                           const float* bq, const float* gq, const float* betaq,
                           const float* bk, const float* gk, const float* betak,
                           const float* bv, const float* gv, const float* betav,
                           float* __restrict__ Wp, float* __restrict__ cvec) {
    const int o = blockIdx.x, t = blockIdx.y, tid = threadIdx.x;
    const float* Wt  = t == 0 ? Wq : (t == 1 ? Wk : Wv);
    const float* bt  = t == 0 ? bq : (t == 1 ? bk : bv);
    const float* gt  = t == 0 ? gq : (t == 1 ? gk : gv);
    const float* bet = t == 0 ? betaq : (t == 1 ? betak : betav);
    __shared__ float wrow[256];
    __shared__ float red[256];
    wrow[tid] = Wt[o * 256 + tid];
    __syncthreads();
    const float* grow = Ghat + (long)tid * 256;
    float tj = 0.f;
    #pragma unroll 8
    for (int k = 0; k < 256; k += 4) {
        const float4 g = *(const float4*)&grow[k];
        tj += g.x * wrow[k] + g.y * wrow[k + 1] + g.z * wrow[k + 2] + g.w * wrow[k + 3];
    }
    const float q2 = block_reduce(wrow[tid] * tj, red, tid);
    const float wx = block_reduce(wrow[tid] * xbar[tid], red, tid);
    const float bo = bt[o];
    const float mu = wx + bo;
    const float var = q2 + 2.f * bo * mu - bo * bo - mu * mu;
    const float a = gt[o] * rsqrtf(var + EPSV);
    Wp[(long)t * 65536 + o * 256 + tid] = a * wrow[tid];
    if (tid == 0) cvec[t * 256 + o] = a * (bo - mu) + bet[o];
}

// ---- u_b = Wv' s_b ; w_b = Wk' s_b ; y = Wk'^T cq ; r = Wq'^T ck ----
__global__ void vec1_kernel(const float* __restrict__ Wp, const float* __restrict__ s,
                            const float* __restrict__ cvec, float* __restrict__ u,
                            float* __restrict__ w, float* __restrict__ y,
                            float* __restrict__ r) {
    const int bidx = blockIdx.x, tid = threadIdx.x;
    __shared__ float sh[256];
    if (bidx < 8) {
        sh[tid] = s[bidx * CC + tid]; __syncthreads();
        float uu = 0.f, ww = 0.f;
        for (int j = 0; j < 256; ++j) {
            uu += Wp[2 * 65536 + tid * 256 + j] * sh[j];
            ww += Wp[1 * 65536 + tid * 256 + j] * sh[j];
        }
        u[bidx * CC + tid] = uu; w[bidx * CC + tid] = ww;
    } else if (bidx == 8) {
        sh[tid] = cvec[0 * 256 + tid]; __syncthreads();
        float yy = 0.f;
        for (int o = 0; o < 256; ++o) yy += Wp[1 * 65536 + o * 256 + tid] * sh[o];
        y[tid] = yy;
    } else {
        sh[tid] = cvec[1 * 256 + tid]; __syncthreads();
        float rr = 0.f;
        for (int o = 0; o < 256; ++o) rr += Wp[0 * 65536 + o * 256 + tid] * sh[o];
        r[tid] = rr;
    }
}

// ---- h_b = Wq'^T w_b ; gy_b = G_b y ----
__global__ void vec2_kernel(const float* __restrict__ Wp, const float* __restrict__ G,
                            const float* __restrict__ w, const float* __restrict__ y,
                            float* __restrict__ h, float* __restrict__ gy) {
    const int b = blockIdx.x, tid = threadIdx.x;
    __shared__ float wl[256];
    __shared__ float yl[256];
    wl[tid] = w[b * CC + tid]; yl[tid] = y[tid]; __syncthreads();
    float hh = 0.f, gg = 0.f;
    for (int o = 0; o < 256; ++o) hh += Wp[0 * 65536 + o * 256 + tid] * wl[o];
    for (int j = 0; j < 256; ++j) gg += G[(long)b * 65536 + tid * 256 + j] * yl[j];
    h[b * CC + tid] = hh; gy[b * CC + tid] = gg;
}

// ---- generic 64x64-tile fp32 GEMM (for the small 256^3 products) ----
__global__ void gemm64(const float* __restrict__ A, const float* __restrict__ B,
                       float* __restrict__ Cm, int M, int N, int K,
                       int transA, int transB, long sA, long sB, long sC) {
    __shared__ float As[16][68];
    __shared__ float Bs[16][68];
    const int tx = threadIdx.x, ty = threadIdx.y;
    const int tid = ty * 16 + tx;
    const int n0 = blockIdx.x * 64, m0 = blockIdx.y * 64, bz = blockIdx.z;
    A += (long)bz * sA; B += (long)bz * sB; Cm += (long)bz * sC;
    float acc[4][4] = {};
    for (int k0 = 0; k0 < K; k0 += 16) {
        if (!transA) {
            for (int l = tid; l < 1024; l += 256) {
                const int mm = l >> 4, kk = l & 15;
                As[kk][mm] = A[(long)(m0 + mm) * K + k0 + kk];
            }
        } else {
            for (int l = tid; l < 1024; l += 256) {
                const int kk = l >> 6, mm = l & 63;
                As[kk][mm] = A[(long)(k0 + kk) * M + m0 + mm];
            }
        }
        if (!transB) {
            for (int l = tid; l < 1024; l += 256) {
                const int kk = l >> 6, nn = l & 63;
                Bs[kk][nn] = B[(long)(k0 + kk) * N + n0 + nn];
            }
        } else {
            for (int l = tid; l < 1024; l += 256) {
                const int nn = l >> 4, kk = l & 15;
                Bs[kk][nn] = B[(long)(n0 + nn) * K + k0 + kk];
            }
        }
        __syncthreads();
        #pragma unroll
        for (int kk = 0; kk < 16; ++kk) {
            const float4 a4 = *(const float4*)&As[kk][ty * 4];
            const float4 b4 = *(const float4*)&Bs[kk][tx * 4];
            const float av[4] = {a4.x, a4.y, a4.z, a4.w};
            const float bv[4] = {b4.x, b4.y, b4.z, b4.w};
            #pragma unroll
            for (int a = 0; a < 4; ++a)
                #pragma unroll
                for (int q = 0; q < 4; ++q) acc[a][q] += av[a] * bv[q];
        }
        __syncthreads();
    }
    #pragma unroll
    for (int a = 0; a < 4; ++a)
        #pragma unroll
        for (int q = 0; q < 4; ++q)
            Cm[(long)(m0 + ty * 4 + a) * N + n0 + tx * 4 + q] = acc[a][q];
}

// ---- off_b assembly + T rank-1 updates + scale; writes bf16 T ----
__global__ void finalize_kernel(const float* __restrict__ Wp, const float* __restrict__ cvec,
                                const float* __restrict__ u, const float* __restrict__ w,
                                const float* __restrict__ hb, const float* __restrict__ gy,
                                const float* __restrict__ r, float* __restrict__ offv,
                                const float* __restrict__ T, ushort* __restrict__ Tbf) {
    const int b = blockIdx.x, tid = threadIdx.x;
    __shared__ float gyl[256];
    __shared__ float red[256];
    __shared__ float ul[256];
    __shared__ float cvl[256];
    gyl[tid] = gy[b * CC + tid];
    ul[tid] = u[b * CC + tid];
    cvl[tid] = cvec[2 * 256 + tid];
    __syncthreads();
    float vg = 0.f;
    for (int j = 0; j < 256; ++j) vg += Wp[2 * 65536 + tid * 256 + j] * gyl[j];
    const float cq_ = cvec[0 * 256 + tid], ck_ = cvec[1 * 256 + tid];
    const float dkq = block_reduce(cq_ * ck_, red, tid);
    const float dwq = block_reduce(w[b * CC + tid] * cq_, red, tid);
    offv[b * CC + tid] = SCALEV * (vg + ul[tid] * dkq + cvl[tid] * (dwq + 4096.0f * dkq));
    __syncthreads();
    const float rv = r[tid];
    const float hv = hb[b * CC + tid];
    const float t2 = hv + 4096.0f * rv;
    const long base = (long)b * 65536;
    for (int i = 0; i < 256; ++i) {
        const long idx = base + (long)i * 256 + tid;
        const float val = SCALEV * (T[idx] + ul[i] * rv + cvl[i] * t2);
        Tbf[idx] = f2bf(val);
    }
}

// ---- out_b = T_b x_b + off_b via MFMA; grid (128 ptiles, 8 b) ----
__global__ __launch_bounds__(256) void out_mfma(const ushort* __restrict__ Tbf,
                                                const float* __restrict__ x,
                                                const float* __restrict__ offv,
                                                float* __restrict__ out) {
    __shared__ __align__(16) ushort Bs[32 * 264];
    const int tid = threadIdx.x;
    const int p0 = blockIdx.x * 32;
    const int b = blockIdx.y;
    const float* xb = x + (long)b * CC * NPIX;
    const ushort* Tb = Tbf + (long)b * 65536;

    // stage x chunk transposed to Bs[pixel][k] as bf16
    const int kg = tid >> 3, pg = tid & 7;
    const int p = pg * 4;
    #pragma unroll
    for (int kt = 0; kt < 256; kt += 128) {
        const int k = kt + kg * 4;
        const float4 v0 = *(const float4*)&xb[(long)(k + 0) * NPIX + p0 + p];
        const float4 v1 = *(const float4*)&xb[(long)(k + 1) * NPIX + p0 + p];
        const float4 v2 = *(const float4*)&xb[(long)(k + 2) * NPIX + p0 + p];
        const float4 v3 = *(const float4*)&xb[(long)(k + 3) * NPIX + p0 + p];
        ushort4 w;
        w.x = f2bf(v0.x); w.y = f2bf(v1.x); w.z = f2bf(v2.x); w.w = f2bf(v3.x);
        *(ushort4*)&Bs[(p + 0) * 264 + k] = w;
        w.x = f2bf(v0.y); w.y = f2bf(v1.y); w.z = f2bf(v2.y); w.w = f2bf(v3.y);
        *(ushort4*)&Bs[(p + 1) * 264 + k] = w;
        w.x = f2bf(v0.z); w.y = f2bf(v1.z); w.z = f2bf(v2.z); w.w = f2bf(v3.z);
        *(ushort4*)&Bs[(p + 2) * 264 + k] = w;
        w.x = f2bf(v0.w); w.y = f2bf(v1.w); w.z = f2bf(v2.w); w.w = f2bf(v3.w);
        *(ushort4*)&Bs[(p + 3) * 264 + k] = w;
    }
    __syncthreads();

    const int wave = tid >> 6, lane = tid & 63;
    const int rbase = wave * 64;
    const int m = lane & 15, q8 = (lane >> 4) * 8;
    f32x4 acc[4][2];
    #pragma unroll
    for (int a = 0; a < 4; ++a)
        #pragma unroll
        for (int q = 0; q < 2; ++q) acc[a][q] = (f32x4){0.f, 0.f, 0.f, 0.f};

    #pragma unroll
    for (int kk = 0; kk < 8; ++kk) {
        short8 af[4], bfr[2];
        #pragma unroll
        for (int a = 0; a < 4; ++a)
            af[a] = *(const short8*)&Tb[(rbase + a * 16 + m) * 256 + kk * 32 + q8];
        #pragma unroll
        for (int q = 0; q < 2; ++q)
            bfr[q] = *(const short8*)&Bs[(q * 16 + m) * 264 + kk * 32 + q8];
        #pragma unroll
        for (int a = 0; a < 4; ++a)
            #pragma unroll
            for (int q = 0; q < 2; ++q)
                acc[a][q] = MFMA16(af[a], bfr[q], acc[a][q]);
    }

    const int rq = (lane >> 4) * 4;
    #pragma unroll
    for (int a = 0; a < 4; ++a) {
        #pragma unroll
        for (int reg = 0; reg < 4; ++reg) {
            const int row = rbase + a * 16 + rq + reg;
            const float off_ = offv[b * CC + row];
            #pragma unroll
            for (int q = 0; q < 2; ++q)
                out[((long)b * CC + row) * NPIX + p0 + q * 16 + m] = acc[a][q][reg] + off_;
        }
    }
}

extern "C" void kernel_launch(void* const* d_in, const int* in_sizes, int n_in,
                              void* d_out, int out_size, void* d_ws, size_t ws_size,
                              hipStream_t stream) {
    const float* x     = (const float*)d_in[0];
    const float* Wq    = (const float*)d_in[1];
    const float* bq    = (const float*)d_in[2];
    const float* gq    = (const float*)d_in[3];
    const float* betaq = (const float*)d_in[4];
    const float* Wk    = (const float*)d_in[5];
    const float* bk    = (const float*)d_in[6];
    const float* gk    = (const float*)d_in[7];
    const float* betak = (const float*)d_in[8];
    const float* Wv    = (const float*)d_in[9];
    const float* bv    = (const float*)d_in[10];
    const float* gv    = (const float*)d_in[11];
    const float* betav = (const float*)d_in[12];
    float* ws = (float*)d_ws;

    float* G    = ws + OFF_G;
    float* S    = ws + OFF_S;
    float* Ghat = ws + OFF_GHAT;
    float* xbar = ws + OFF_XBAR;
    float* Wp   = ws + OFF_WP;
    float* cvec = ws + OFF_CVEC;
    float* U    = ws + OFF_U;
    float* W_   = ws + OFF_W;
    float* Hb   = ws + OFF_HB;
    float* Gy   = ws + OFF_GY;
    float* Y    = ws + OFF_Y;
    float* R    = ws + OFF_R;
    float* OffV = ws + OFF_OFFV;
    float* Z    = ws + OFF_Z;
    float* F    = ws + OFF_F;
    float* T    = ws + OFF_T;
    ushort* Tbf = (ushort*)(ws + OFF_TBF);

    // zero atomicAdd targets (G, S)
    hipMemsetAsync(d_ws, 0, (size_t)(OFF_S + BB * CC) * sizeof(float), stream);

    gram_mfma<<<dim3(32, 8, 3), 256, 0, stream>>>(x, G, S);
    mirror_reduce<<<257, 256, 0, stream>>>(G, S, Ghat, xbar);
    stats_quad<<<dim3(256, 3), 256, 0, stream>>>(Wq, Wk, Wv, Ghat, xbar,
                                                 bq, gq, betaq, bk, gk, betak,
                                                 bv, gv, betav, Wp, cvec);
    vec1_kernel<<<10, 256, 0, stream>>>(Wp, S, cvec, U, W_, Y, R);
    // Z = Wk'^T @ Wq'
    gemm64<<<dim3(4, 4, 1), dim3(16, 16), 0, stream>>>(Wp + 65536, Wp, Z, 256, 256, 256,
                                                       1, 0, 0L, 0L, 0L);
    vec2_kernel<<<8, 256, 0, stream>>>(Wp, G, W_, Y, Hb, Gy);
    // F_b = G_b @ Z
    gemm64<<<dim3(4, 4, 8), dim3(16, 16), 0, stream>>>(G, Z, F, 256, 256, 256,
                                                       0, 0, 65536L, 0L, 65536L);
    // T_b = Wv' @ F_b
    gemm64<<<dim3(4, 4, 8), dim3(16, 16), 0, stream>>>(Wp + 2 * 65536, F, T, 256, 256, 256,
                                                       0, 0, 0L, 65536L, 65536L);
    finalize_kernel<<<8, 256, 0, stream>>>(Wp, cvec, U, W_, Hb, Gy, R, OffV, T, Tbf);
    out_mfma<<<dim3(128, 8), 256, 0, stream>>>(Tbf, x, OffV, (float*)d_out);
}

// Round 4
// 260.403 us; speedup vs baseline: 1.9236x; 1.3811x over previous
//
#include <hip/hip_runtime.h>

// PatchAttentionLayer, fully restructured:
//   G_b = x_b x_b^T (Gram, bf16 MFMA, upper tiles + mirror), s_b = x_b 1
//   BN stats analytic (quadratic form on Ghat); Wp = diag(a)W, cvec.
//   Z = Wk'^T Wq'; F_b = G_b Z; T_b = Wv' F_b + rank-1; out = T_b x_b + off 1^T.
// Middle GEMMs: bf16 MFMA, fragments straight from L2 (no LDS).
// R3 bug: Gbf/FT/TBF sized at half their true footprint (ushort-vs-float) ->
// internal overlap -> garbage. R4 = identical algorithm, corrected layout.

#define BB 8
#define CC 256
#define NPIX 4096
#define PTOT 32768
#define EPSV 1e-5f
#define SCALEV 0.125f

// ---- workspace layout (float offsets; ushort buffers = count/2 floats) ----
#define OFF_G     0L          // 524288 floats (8*256*256)
#define OFF_S     524288L     // 2048
#define OFF_GHAT  526336L     // 65536
#define OFF_XBAR  591872L     // 256
#define OFF_WP    592128L     // 196608
#define OFF_CVEC  788736L     // 768
#define OFF_U     789504L     // 2048
#define OFF_HB    791552L     // 2048
#define OFF_R     793600L     // 256
#define OFF_OFFV  793856L     // 2048
#define OFF_GBF   795904L     // 8*65536 ushort = 262144 floats
#define OFF_WQT   1058048L    // 65536 ushort = 32768 floats
#define OFF_WKT   1090816L    // 32768 floats
#define OFF_WVB   1123584L    // 32768 floats
#define OFF_ZT    1156352L    // 32768 floats
#define OFF_FT    1189120L    // 8*65536 ushort = 262144 floats
#define OFF_TBF   1451264L    // 262144 floats
// total 1713408 floats = 6.85 MB

typedef __attribute__((ext_vector_type(8))) short short8;
typedef __attribute__((ext_vector_type(4))) float f32x4;

#define MFMA16(a, b, c) __builtin_amdgcn_mfma_f32_16x16x32_bf16((a), (b), (c), 0, 0, 0)

__device__ __forceinline__ ushort f2bf(float f) {
    union { float f; unsigned u; } v; v.f = f;
    const unsigned r = (v.u + 0x7FFFu + ((v.u >> 16) & 1u)) >> 16;
    return (ushort)r;
}

__device__ __forceinline__ float block_reduce(float v, float* red, int tid) {
    red[tid] = v; __syncthreads();
    for (int st = 128; st > 0; st >>= 1) {
        if (tid < st) red[tid] += red[tid + st];
        __syncthreads();
    }
    float r = red[0]; __syncthreads();
    return r;
}

// ---- Gram via MFMA: 64x64 upper-triangle tiles, ks=8 K-split, rowsum fused ----
// grid (8 ks, 8 b, 10 tiles)
__global__ __launch_bounds__(256) void gram_mfma(const float* __restrict__ x,
                                                 float* __restrict__ G,
                                                 float* __restrict__ S) {
    __shared__ __align__(16) ushort Ab[64 * 72];
    __shared__ __align__(16) ushort Bb[64 * 72];
    __shared__ float rs[64];
    const int tid = threadIdx.x;
    const int ks = blockIdx.x, b = blockIdx.y, tt = blockIdx.z;
    const int itA[10] = {0,0,0,0,1,1,1,2,2,3};
    const int jtA[10] = {0,1,2,3,1,2,3,2,3,3};
    const int it = itA[tt], jt = jtA[tt];
    const bool diag = (it == jt);
    const int i0 = it * 64, j0 = jt * 64, k0 = ks * 512;
    const float* xb = x + (long)b * CC * NPIX;
    const int c = tid & 15, rp = tid >> 4;
    const int wave = tid >> 6, lane = tid & 63;
    const int wr = (wave >> 1) * 32, wc = (wave & 1) * 32;
    const int m = lane & 15, q8 = (lane >> 4) * 8;

    if (tid < 64) rs[tid] = 0.f;
    float rloc[4] = {0.f, 0.f, 0.f, 0.f};
    f32x4 acc[2][2];
    #pragma unroll
    for (int a = 0; a < 2; ++a)
        #pragma unroll
        for (int q = 0; q < 2; ++q) acc[a][q] = (f32x4){0.f, 0.f, 0.f, 0.f};

    for (int kc = 0; kc < 512; kc += 64) {
        __syncthreads();
        #pragma unroll
        for (int pp = 0; pp < 4; ++pp) {
            const int row = pp * 16 + rp;
            const float4 v = *(const float4*)&xb[(long)(i0 + row) * NPIX + k0 + kc + c * 4];
            rloc[pp] += v.x + v.y + v.z + v.w;
            ushort4 w;
            w.x = f2bf(v.x); w.y = f2bf(v.y); w.z = f2bf(v.z); w.w = f2bf(v.w);
            *(ushort4*)&Ab[row * 72 + c * 4] = w;
        }
        if (!diag) {
            #pragma unroll
            for (int pp = 0; pp < 4; ++pp) {
                const int row = pp * 16 + rp;
                const float4 v = *(const float4*)&xb[(long)(j0 + row) * NPIX + k0 + kc + c * 4];
                ushort4 w;
                w.x = f2bf(v.x); w.y = f2bf(v.y); w.z = f2bf(v.z); w.w = f2bf(v.w);
                *(ushort4*)&Bb[row * 72 + c * 4] = w;
            }
        }
        __syncthreads();
        const ushort* Bsrc = diag ? Ab : Bb;
        #pragma unroll
        for (int kk = 0; kk < 2; ++kk) {
            short8 af[2], bfv[2];
            #pragma unroll
            for (int a = 0; a < 2; ++a)
                af[a] = *(const short8*)&Ab[(wr + a * 16 + m) * 72 + kk * 32 + q8];
            #pragma unroll
            for (int q = 0; q < 2; ++q)
                bfv[q] = *(const short8*)&Bsrc[(wc + q * 16 + m) * 72 + kk * 32 + q8];
            #pragma unroll
            for (int a = 0; a < 2; ++a)
                #pragma unroll
                for (int q = 0; q < 2; ++q)
                    acc[a][q] = MFMA16(af[a], bfv[q], acc[a][q]);
        }
    }
    if (diag) {
        #pragma unroll
        for (int pp = 0; pp < 4; ++pp) atomicAdd(&rs[pp * 16 + rp], rloc[pp]);
        __syncthreads();
        if (tid < 64) atomicAdd(&S[b * CC + i0 + tid], rs[tid]);
    }
    float* Gb = G + (long)b * 65536;
    const int rq = (lane >> 4) * 4;
    #pragma unroll
    for (int a = 0; a < 2; ++a) {
        #pragma unroll
        for (int q = 0; q < 2; ++q) {
            const int gj = j0 + wc + q * 16 + m;
            #pragma unroll
            for (int reg = 0; reg < 4; ++reg)
                atomicAdd(&Gb[(long)(i0 + wr + a * 16 + rq + reg) * 256 + gj], acc[a][q][reg]);
        }
    }
}

// ---- mirror lower 64-tiles of G_b; emit Gbf (bf16); Ghat; xbar ----
__global__ void mirror_reduce(float* __restrict__ G, const float* __restrict__ S,
                              float* __restrict__ Ghat, float* __restrict__ xbar,
                              ushort* __restrict__ Gbf) {
    const int i = blockIdx.x, tid = threadIdx.x;
    if (i < 256) {
        float sum = 0.f;
        if ((i >> 6) > (tid >> 6)) {
            for (int b = 0; b < BB; ++b) {
                const float v = G[(long)b * 65536 + (long)tid * 256 + i];
                G[(long)b * 65536 + (long)i * 256 + tid] = v;
                Gbf[(long)b * 65536 + (long)i * 256 + tid] = f2bf(v);
                sum += v;
            }
        } else {
            for (int b = 0; b < BB; ++b) {
                const float v = G[(long)b * 65536 + (long)i * 256 + tid];
                Gbf[(long)b * 65536 + (long)i * 256 + tid] = f2bf(v);
                sum += v;
            }
        }
        Ghat[i * 256 + tid] = sum * (1.0f / PTOT);
    } else {
        float sum = 0.f;
        for (int b = 0; b < BB; ++b) sum += S[b * CC + tid];
        xbar[tid] = sum * (1.0f / PTOT);
    }
}

// ---- BN stats; writes fp32 Wp, bf16 WqT/WkT (transposed), Wvb (row-major), cvec ----
__global__ void stats_quad(const float* __restrict__ Wq, const float* __restrict__ Wk,
                           const float* __restrict__ Wv, const float* __restrict__ Ghat,
                           const float* __restrict__ xbar,
                           const float* bq, const float* gq, const float* betaq,
                           const float* bk, const float* gk, const float* betak,
                           const float* bv, const float* gv, const float* betav,
                           float* __restrict__ Wp, float* __restrict__ cvec,
                           ushort* __restrict__ WqT, ushort* __restrict__ WkT,
                           ushort* __restrict__ Wvb) {
    const int o = blockIdx.x, t = blockIdx.y, tid = threadIdx.x;
    const float* Wt  = t == 0 ? Wq : (t == 1 ? Wk : Wv);
    const float* bt  = t == 0 ? bq : (t == 1 ? bk : bv);
    const float* gt  = t == 0 ? gq : (t == 1 ? gk : gv);
    const float* bet = t == 0 ? betaq : (t == 1 ? betak : betav);
    __shared__ float wrow[256];
    __shared__ float red[256];
    wrow[tid] = Wt[o * 256 + tid];
    __syncthreads();
    const float* grow = Ghat + (long)tid * 256;
    float tj = 0.f;
    #pragma unroll 8
    for (int k = 0; k < 256; k += 4) {
        const float4 g = *(const float4*)&grow[k];
        tj += g.x * wrow[k] + g.y * wrow[k + 1] + g.z * wrow[k + 2] + g.w * wrow[k + 3];
    }
    const float q2 = block_reduce(wrow[tid] * tj, red, tid);
    const float wx = block_reduce(wrow[tid] * xbar[tid], red, tid);
    const float bo = bt[o];
    const float mu = wx + bo;
    const float var = q2 + 2.f * bo * mu - bo * bo - mu * mu;
    const float a = gt[o] * rsqrtf(var + EPSV);
    const float wpv = a * wrow[tid];
    Wp[(long)t * 65536 + o * 256 + tid] = wpv;
    const ushort wb = f2bf(wpv);
    if (t == 0)      WqT[(long)tid * 256 + o] = wb;
    else if (t == 1) WkT[(long)tid * 256 + o] = wb;
    else             Wvb[(long)o * 256 + tid] = wb;
    if (tid == 0) cvec[t * 256 + o] = a * (bo - mu) + bet[o];
}

// ---- fused per-batch vector work: u,w,h,r,y,gy,vg,offv ----
__global__ void mid1(const float* __restrict__ Wp, const float* __restrict__ G,
                     const float* __restrict__ S, const float* __restrict__ cvec,
                     float* __restrict__ u, float* __restrict__ hb,
                     float* __restrict__ r_out, float* __restrict__ offv) {
    const int b = blockIdx.x, tid = threadIdx.x;
    const float* Wq_ = Wp, *Wk_ = Wp + 65536, *Wv_ = Wp + 131072;
    __shared__ float sh[256], red[256], wl[256], yl[256], gyl[256], cqs[256], cks[256];
    sh[tid]  = S[b * 256 + tid];
    cqs[tid] = cvec[tid];
    cks[tid] = cvec[256 + tid];
    const float cv = cvec[512 + tid];
    __syncthreads();
    float uu = 0.f, ww = 0.f;
    for (int j = 0; j < 256; ++j) {
        uu += Wv_[(long)tid * 256 + j] * sh[j];
        ww += Wk_[(long)tid * 256 + j] * sh[j];
    }
    u[b * 256 + tid] = uu;
    wl[tid] = ww;
    __syncthreads();
    float yy = 0.f, rr = 0.f, hh = 0.f;
    for (int o = 0; o < 256; ++o) {
        const float wk = Wk_[(long)o * 256 + tid];
        const float wq = Wq_[(long)o * 256 + tid];
        yy += wk * cqs[o];
        rr += wq * cks[o];
        hh += wq * wl[o];
    }
    yl[tid] = yy;
    r_out[tid] = rr;            // identical in every block; benign
    hb[b * 256 + tid] = hh;
    __syncthreads();
    float gg = 0.f;
    for (int j = 0; j < 256; ++j) gg += G[(long)b * 65536 + (long)tid * 256 + j] * yl[j];
    gyl[tid] = gg;
    __syncthreads();
    float vg = 0.f;
    for (int j = 0; j < 256; ++j) vg += Wv_[(long)tid * 256 + j] * gyl[j];
    const float dkq = block_reduce(cqs[tid] * cks[tid], red, tid);
    const float dwq = block_reduce(wl[tid] * cqs[tid], red, tid);
    offv[b * 256 + tid] = SCALEV * (vg + uu * dkq + cv * (dwq + 4096.0f * dkq));
}

// ---- bf16 MFMA 128x128-tile GEMM, K=256, fragments direct from L2 ----
// mode 0: store D^T plain bf16.  mode 1: rank-1 epilogue + scale, row-major.
__global__ __launch_bounds__(256) void gemm_mid(const ushort* __restrict__ A, long sA,
                                                const ushort* __restrict__ B, long sB,
                                                ushort* __restrict__ D, long sD, int mode,
                                                const float* __restrict__ u,
                                                const float* __restrict__ cvec,
                                                const float* __restrict__ r,
                                                const float* __restrict__ hb) {
    const int n0 = blockIdx.x * 128, m0 = blockIdx.y * 128, bz = blockIdx.z;
    const ushort* Ab = A + (long)bz * sA;
    const ushort* Bb = B + (long)bz * sB;
    ushort* Db = D + (long)bz * sD;
    const int tid = threadIdx.x, wave = tid >> 6, lane = tid & 63;
    const int wr = (wave >> 1) * 64, wc = (wave & 1) * 64;
    const int m = lane & 15, q8 = (lane >> 4) * 8;
    f32x4 acc[4][4];
    #pragma unroll
    for (int a = 0; a < 4; ++a)
        #pragma unroll
        for (int q = 0; q < 4; ++q) acc[a][q] = (f32x4){0.f, 0.f, 0.f, 0.f};
    #pragma unroll
    for (int kk = 0; kk < 8; ++kk) {
        short8 af[4], bfv[4];
        #pragma unroll
        for (int a = 0; a < 4; ++a)
            af[a] = *(const short8*)&Ab[(long)(m0 + wr + a * 16 + m) * 256 + kk * 32 + q8];
        #pragma unroll
        for (int q = 0; q < 4; ++q)
            bfv[q] = *(const short8*)&Bb[(long)(n0 + wc + q * 16 + m) * 256 + kk * 32 + q8];
        #pragma unroll
        for (int a = 0; a < 4; ++a)
            #pragma unroll
            for (int q = 0; q < 4; ++q)
                acc[a][q] = MFMA16(af[a], bfv[q], acc[a][q]);
    }
    const int rq = (lane >> 4) * 4;
    #pragma unroll
    for (int a = 0; a < 4; ++a) {
        #pragma unroll
        for (int q = 0; q < 4; ++q) {
            const int col = n0 + wc + q * 16 + m;
            #pragma unroll
            for (int reg = 0; reg < 4; ++reg) {
                const int row = m0 + wr + a * 16 + rq + reg;
                const float v = acc[a][q][reg];
                if (mode == 0) {
                    Db[(long)col * 256 + row] = f2bf(v);
                } else {
                    const float rv = r[col];
                    const float t2 = hb[bz * 256 + col] + 4096.0f * rv;
                    const float val = SCALEV * (v + u[bz * 256 + row] * rv + cvec[512 + row] * t2);
                    Db[(long)row * 256 + col] = f2bf(val);
                }
            }
        }
    }
}

// ---- out_b = T_b x_b + off_b via MFMA; 64-pixel tiles; grid (64, 8) ----
__global__ __launch_bounds__(256) void out_mfma(const ushort* __restrict__ Tbf,
                                                const float* __restrict__ x,
                                                const float* __restrict__ offv,
                                                float* __restrict__ out) {
    __shared__ __align__(16) ushort Bs[64 * 264];
    const int tid = threadIdx.x;
    const int p0 = blockIdx.x * 64;
    const int b = blockIdx.y;
    const float* xb = x + (long)b * CC * NPIX;
    const ushort* Tb = Tbf + (long)b * 65536;

    // stage x[0:256, p0:p0+64] transposed -> Bs[pixel][k] bf16
    const int c = tid & 15, kq = tid >> 4;
    #pragma unroll
    for (int kt = 0; kt < 4; ++kt) {
        const int k4 = kt * 64 + kq * 4;
        const int p = c * 4;
        const float4 v0 = *(const float4*)&xb[(long)(k4 + 0) * NPIX + p0 + p];
        const float4 v1 = *(const float4*)&xb[(long)(k4 + 1) * NPIX + p0 + p];
        const float4 v2 = *(const float4*)&xb[(long)(k4 + 2) * NPIX + p0 + p];
        const float4 v3 = *(const float4*)&xb[(long)(k4 + 3) * NPIX + p0 + p];
        ushort4 w;
        w.x = f2bf(v0.x); w.y = f2bf(v1.x); w.z = f2bf(v2.x); w.w = f2bf(v3.x);
        *(ushort4*)&Bs[(p + 0) * 264 + k4] = w;
        w.x = f2bf(v0.y); w.y = f2bf(v1.y); w.z = f2bf(v2.y); w.w = f2bf(v3.y);
        *(ushort4*)&Bs[(p + 1) * 264 + k4] = w;
        w.x = f2bf(v0.z); w.y = f2bf(v1.z); w.z = f2bf(v2.z); w.w = f2bf(v3.z);
        *(ushort4*)&Bs[(p + 2) * 264 + k4] = w;
        w.x = f2bf(v0.w); w.y = f2bf(v1.w); w.z = f2bf(v2.w); w.w = f2bf(v3.w);
        *(ushort4*)&Bs[(p + 3) * 264 + k4] = w;
    }
    __syncthreads();

    const int wave = tid >> 6, lane = tid & 63;
    const int wr = wave * 64;
    const int m = lane & 15, q8 = (lane >> 4) * 8;
    f32x4 acc[4][4];
    #pragma unroll
    for (int a = 0; a < 4; ++a)
        #pragma unroll
        for (int q = 0; q < 4; ++q) acc[a][q] = (f32x4){0.f, 0.f, 0.f, 0.f};

    #pragma unroll
    for (int kk = 0; kk < 8; ++kk) {
        short8 af[4], bfv[4];
        #pragma unroll
        for (int a = 0; a < 4; ++a)
            af[a] = *(const short8*)&Tb[(long)(wr + a * 16 + m) * 256 + kk * 32 + q8];
        #pragma unroll
        for (int q = 0; q < 4; ++q)
            bfv[q] = *(const short8*)&Bs[(q * 16 + m) * 264 + kk * 32 + q8];
        #pragma unroll
        for (int a = 0; a < 4; ++a)
            #pragma unroll
            for (int q = 0; q < 4; ++q)
                acc[a][q] = MFMA16(af[a], bfv[q], acc[a][q]);
    }

    const int rq = (lane >> 4) * 4;
    #pragma unroll
    for (int a = 0; a < 4; ++a) {
        #pragma unroll
        for (int reg = 0; reg < 4; ++reg) {
            const int row = wr + a * 16 + rq + reg;
            const float off_ = offv[b * CC + row];
            float* orow = &out[((long)b * CC + row) * NPIX + p0];
            #pragma unroll
            for (int q = 0; q < 4; ++q)
                orow[q * 16 + m] = acc[a][q][reg] + off_;
        }
    }
}

extern "C" void kernel_launch(void* const* d_in, const int* in_sizes, int n_in,
                              void* d_out, int out_size, void* d_ws, size_t ws_size,
                              hipStream_t stream) {
    const float* x     = (const float*)d_in[0];
    const float* Wq    = (const float*)d_in[1];
    const float* bq    = (const float*)d_in[2];
    const float* gq    = (const float*)d_in[3];
    const float* betaq = (const float*)d_in[4];
    const float* Wk    = (const float*)d_in[5];
    const float* bk    = (const float*)d_in[6];
    const float* gk    = (const float*)d_in[7];
    const float* betak = (const float*)d_in[8];
    const float* Wv    = (const float*)d_in[9];
    const float* bv    = (const float*)d_in[10];
    const float* gv    = (const float*)d_in[11];
    const float* betav = (const float*)d_in[12];
    float* ws = (float*)d_ws;

    float*  G    = ws + OFF_G;
    float*  S    = ws + OFF_S;
    float*  Ghat = ws + OFF_GHAT;
    float*  xbar = ws + OFF_XBAR;
    float*  Wp   = ws + OFF_WP;
    float*  cvec = ws + OFF_CVEC;
    float*  U    = ws + OFF_U;
    float*  Hb   = ws + OFF_HB;
    float*  R    = ws + OFF_R;
    float*  OffV = ws + OFF_OFFV;
    ushort* Gbf  = (ushort*)(ws + OFF_GBF);
    ushort* WqT  = (ushort*)(ws + OFF_WQT);
    ushort* WkT  = (ushort*)(ws + OFF_WKT);
    ushort* Wvb  = (ushort*)(ws + OFF_WVB);
    ushort* ZT   = (ushort*)(ws + OFF_ZT);
    ushort* FT   = (ushort*)(ws + OFF_FT);
    ushort* Tbf  = (ushort*)(ws + OFF_TBF);

    // zero atomicAdd targets (G, S)
    hipMemsetAsync(d_ws, 0, (size_t)(OFF_S + BB * CC) * sizeof(float), stream);

    gram_mfma<<<dim3(8, 8, 10), 256, 0, stream>>>(x, G, S);
    mirror_reduce<<<257, 256, 0, stream>>>(G, S, Ghat, xbar, Gbf);
    stats_quad<<<dim3(256, 3), 256, 0, stream>>>(Wq, Wk, Wv, Ghat, xbar,
                                                 bq, gq, betaq, bk, gk, betak,
                                                 bv, gv, betav, Wp, cvec,
                                                 WqT, WkT, Wvb);
    // Z = Wk'^T Wq'  -> ZT
    gemm_mid<<<dim3(2, 2, 1), 256, 0, stream>>>(WkT, 0L, WqT, 0L, ZT, 0L, 0,
                                                nullptr, nullptr, nullptr, nullptr);
    mid1<<<8, 256, 0, stream>>>(Wp, G, S, cvec, U, Hb, R, OffV);
    // F_b = G_b Z -> FT
    gemm_mid<<<dim3(2, 2, 8), 256, 0, stream>>>(Gbf, 65536L, ZT, 0L, FT, 65536L, 0,
                                                nullptr, nullptr, nullptr, nullptr);
    // T_b = Wv' F_b + rank-1, scaled -> Tbf
    gemm_mid<<<dim3(2, 2, 8), 256, 0, stream>>>(Wvb, 0L, FT, 65536L, Tbf, 65536L, 1,
                                                U, cvec, R, Hb);
    out_mfma<<<dim3(64, 8), 256, 0, stream>>>(Tbf, x, OffV, (float*)d_out);
}